// Round 15
// baseline (98.093 us; speedup 1.0000x reference)
//
#include <hip/hip_runtime.h>
#include <hip/hip_bf16.h>
#include <math.h>

// Problem constants
#define B_ 8
#define C_ 64
#define H_ 256
#define W_ 256
#define HL_ 128
#define WL_ 128
#define GN_G 8
#define CPG 8
#define GRP 4
#define OC_ 8
#define GROUP_ELEMS (CPG * H_ * W_)   // 524288

#define TILE_H 16       // low-res rows per k2 block
#define XROWS 34        // hi-res rows staged (2*16 + 2 halo)
#define EOW 132         // even/odd array row stride

__device__ __forceinline__ float bf2f(unsigned short u) {
  return __uint_as_float(((unsigned)u) << 16);
}
__device__ __forceinline__ unsigned short f2bfbits(float f) {
  __hip_bfloat16 h = __float2bfloat16(f);
  return *reinterpret_cast<unsigned short*>(&h);
}

// ---------------- Kernel 2 (v4): GN-partials + pool(x) + pool(L(x)) + optional bf16 x copy ----------------
template <int USE_XB>
__global__ __launch_bounds__(256) void k2_fused(const float* __restrict__ x,
                                                const float* __restrict__ hpw,
                                                __hip_bfloat16* __restrict__ px,
                                                __hip_bfloat16* __restrict__ pL,
                                                unsigned short* __restrict__ xb,
                                                float* __restrict__ partials) {
  __shared__ float E[XROWS][EOW];
  __shared__ float O[XROWS][EOW];
  __shared__ float rs[4], rs2[4];
  const int t = threadIdx.x;
  const int blk = blockIdx.x;
  const int tileIdx = blk & 7;
  const int bc = blk >> 3;               // b*64+c
  const int c = bc & 63;
  const int hl0 = tileIdx * TILE_H;
  const float* plane = x + (size_t)bc * (H_ * W_);
  const int y0 = 2 * hl0 - 1;

  if (t < XROWS * 2) {
    const int r = t >> 1;
    if (t & 1) E[r][128] = 0.f; else O[r][0] = 0.f;
  }

  float s = 0.f, s2 = 0.f;
  for (int i = 0; i < 9; ++i) {
    const int q = t + i * 256;
    if (q >= XROWS * 64) break;
    const int r = q >> 6;
    const int k = q & 63;
    const int y = y0 + r;
    float4 v = make_float4(0.f, 0.f, 0.f, 0.f);
    if ((unsigned)y < (unsigned)H_)
      v = *reinterpret_cast<const float4*>(plane + y * W_ + (k << 2));
    E[r][2 * k]     = v.x;
    E[r][2 * k + 1] = v.z;
    O[r][2 * k + 1] = v.y;
    O[r][2 * k + 2] = v.w;
    if (r >= 1 && r <= 32) {
      s  += v.x + v.y + v.z + v.w;
      s2 += v.x * v.x + v.y * v.y + v.z * v.z + v.w * v.w;
      if (USE_XB) {
        ushort4 bv;
        bv.x = f2bfbits(v.x); bv.y = f2bfbits(v.y);
        bv.z = f2bfbits(v.z); bv.w = f2bfbits(v.w);
        *reinterpret_cast<ushort4*>(xb + (size_t)bc * (H_ * W_) + y * W_ + (k << 2)) = bv;
      }
    }
  }
#pragma unroll
  for (int off = 32; off > 0; off >>= 1) {
    s  += __shfl_down(s, off, 64);
    s2 += __shfl_down(s2, off, 64);
  }
  if ((t & 63) == 0) { rs[t >> 6] = s; rs2[t >> 6] = s2; }
  __syncthreads();
  if (t == 0) {
    partials[blk * 2 + 0] = rs[0] + rs[1] + rs[2] + rs[3];
    partials[blk * 2 + 1] = rs2[0] + rs2[1] + rs2[2] + rs2[3];
  }

  float w[9];
#pragma unroll
  for (int i = 0; i < 9; ++i) w[i] = hpw[c * 9 + i];

  const int wl = t & 127;
  const int hs = (t >> 7) * 8;
  const int rbase = 2 * hs;
  float win[4][4];
#pragma unroll
  for (int j = 0; j < 4; ++j) {
    win[j][0] = O[rbase + j][wl];
    win[j][1] = E[rbase + j][wl];
    win[j][2] = O[rbase + j][wl + 1];
    win[j][3] = E[rbase + j][wl + 1];
  }

  int outIdx = (bc * HL_ + (hl0 + hs)) * WL_ + wl;
#pragma unroll
  for (int i = 0; i < 8; ++i) {
    float pr[4][3];
#pragma unroll
    for (int j = 0; j < 4; ++j)
#pragma unroll
      for (int d = 0; d < 3; ++d) pr[j][d] = win[j][d] + win[j][d + 1];
    float hfsum = 0.f;
    float q11 = 0.f;
#pragma unroll
    for (int j = 0; j < 3; ++j)
#pragma unroll
      for (int d = 0; d < 3; ++d) {
        const float qq = pr[j][d] + pr[j + 1][d];
        hfsum = fmaf(w[j * 3 + d], qq, hfsum);
        if (j == 1 && d == 1) q11 = qq;
      }
    px[outIdx] = __float2bfloat16(0.25f * q11);
    pL[outIdx] = __float2bfloat16(0.25f * hfsum);
    outIdx += WL_;
    if (i < 7) {
      const int rn = rbase + 2 * i + 4;
#pragma unroll
      for (int d = 0; d < 4; ++d) {
        win[0][d] = win[2][d];
        win[1][d] = win[3][d];
      }
      win[2][0] = O[rn][wl];     win[2][1] = E[rn][wl];
      win[2][2] = O[rn][wl + 1]; win[2][3] = E[rn][wl + 1];
      win[3][0] = O[rn + 1][wl];     win[3][1] = E[rn + 1][wl];
      win[3][2] = O[rn + 1][wl + 1]; win[3][3] = E[rn + 1][wl + 1];
    }
  }
}

// ---------------- Kernel 34 (v4): inline GN-finalize + offsets + bilinear sample ----------------
// One block = 16x16 pixel tile; single-buffer LDS; ab recomputed per block from partials.
#define TS 16
template <int USE_XB>
__global__ __launch_bounds__(256) void k34_fused(const float* __restrict__ x,
                                                 const unsigned short* __restrict__ xb,
                                                 const __hip_bfloat16* __restrict__ px,
                                                 const __hip_bfloat16* __restrict__ pL,
                                                 const float* __restrict__ partials,
                                                 const float* __restrict__ gamma,
                                                 const float* __restrict__ beta,
                                                 const float* __restrict__ dir_w,
                                                 const float* __restrict__ dir_b,
                                                 const float* __restrict__ mag_w,
                                                 const float* __restrict__ mag_b,
                                                 const float* __restrict__ hfg_w,
                                                 const float* __restrict__ hfg_b,
                                                 float* __restrict__ out) {
  __shared__ float s_v[16][18][24];   // 27.6 KB: affine xl tile + halo (f32)
  __shared__ float s_mw[C_][OC_];
  __shared__ float s_hw[C_][OC_];
  __shared__ float s_dir[OC_][8];
  __shared__ float s_ab2[C_][2];
  __shared__ float s_bias[2][OC_];

  const int tid = threadIdx.x;
  const int bx = blockIdx.x;
  const int tx = bx & 7, ty = (bx >> 3) & 7, b = bx >> 6;
  const int hl0 = ty * TS, wl0 = tx * TS;
  const size_t planeSz = (size_t)HL_ * WL_;

  for (int i = tid; i < OC_ * C_; i += 256) {
    const int o = i >> 6, c = i & 63;
    s_mw[c][o] = mag_w[i];
    s_hw[c][o] = hfg_w[i];
  }
  if (tid < 64) s_dir[tid >> 3][tid & 7] = dir_w[tid];
  if (tid < OC_) { s_bias[0][tid] = mag_b[tid] + hfg_b[tid]; s_bias[1][tid] = dir_b[tid]; }
  // inline GN finalize: per-channel affine from partials (group-redundant, L2-hit)
  if (tid < 64) {
    const int c = tid, g = c >> 3;
    float S = 0.f, S2 = 0.f;
    for (int c2 = g * CPG; c2 < g * CPG + CPG; ++c2)
#pragma unroll
      for (int p2 = 0; p2 < 8; ++p2) {
        const int blk2 = (b * 64 + c2) * 8 + p2;
        S  += partials[blk2 * 2 + 0];
        S2 += partials[blk2 * 2 + 1];
      }
    const float N = (float)GROUP_ELEMS;
    const float mean = S / N;
    const float var = fmaxf(S2 / N - mean * mean, 0.f);
    const float a = rsqrtf(var + 1e-5f) * gamma[c];
    s_ab2[c][0] = a;
    s_ab2[c][1] = beta[c] - mean * a;
  }

  const int pxi = tid & 15, pyi = tid >> 4;
  const int hl = hl0 + pyi, wl = wl0 + pxi;
  const float mterm = 0.5f * ((hl == 0) + (hl == HL_ - 1) + (wl == 0) + (wl == WL_ - 1));

  float dot[8], n2[8], z[8], n1 = 0.f;
#pragma unroll
  for (int k = 0; k < 8; ++k) { dot[k] = 0.f; n2[k] = 0.f; z[k] = 0.f; }

  for (int cc = 0; cc < 4; ++cc) {
    // prefetch pL for this chunk (consumed after barrier; latency overlaps staging)
    float lh[16];
    {
      const unsigned short* lp = reinterpret_cast<const unsigned short*>(
          pL + (size_t)(b * C_ + cc * 16) * planeSz + hl * WL_ + wl);
#pragma unroll
      for (int c = 0; c < 16; ++c) lh[c] = bf2f(lp[c * planeSz]);
    }

    __syncthreads();   // prev chunk compute done; iter0: all shared init done

    // stage 16ch x 18row x 6xfloat4 with affine + border-zero (bf16 source)
    for (int q = tid; q < 16 * 18 * 6; q += 256) {
      const int c = q / 108, rem = q % 108, r = rem / 6, f4 = rem % 6;
      const int cg = cc * 16 + c;
      const int gy = hl0 - 1 + r;
      const int gx0 = wl0 - 4 + f4 * 4;
      const float a = s_ab2[cg][0], bb = s_ab2[cg][1];
      const __hip_bfloat16* pp = px + (size_t)(b * C_ + cg) * planeSz + gy * WL_ + gx0;
      float4 v = make_float4(0.f, 0.f, 0.f, 0.f);
      if ((unsigned)gy < (unsigned)HL_) {
        if (gx0 >= 0 && gx0 + 3 < WL_) {
          const ushort4 rv = *reinterpret_cast<const ushort4*>(pp);   // 8B-aligned
          v.x = fmaf(a, bf2f(rv.x), bb); v.y = fmaf(a, bf2f(rv.y), bb);
          v.z = fmaf(a, bf2f(rv.z), bb); v.w = fmaf(a, bf2f(rv.w), bb);
        } else {
          const unsigned short* ps = reinterpret_cast<const unsigned short*>(pp);
          if ((unsigned)(gx0 + 0) < (unsigned)WL_) v.x = fmaf(a, bf2f(ps[0]), bb);
          if ((unsigned)(gx0 + 1) < (unsigned)WL_) v.y = fmaf(a, bf2f(ps[1]), bb);
          if ((unsigned)(gx0 + 2) < (unsigned)WL_) v.z = fmaf(a, bf2f(ps[2]), bb);
          if ((unsigned)(gx0 + 3) < (unsigned)WL_) v.w = fmaf(a, bf2f(ps[3]), bb);
        }
      }
      *reinterpret_cast<float4*>(&s_v[c][r][f4 * 4]) = v;
    }
    __syncthreads();

#pragma unroll
    for (int c = 0; c < 16; ++c) {
      const int cg = cc * 16 + c;
      const float a = s_ab2[cg][0], bb = s_ab2[cg][1];
      const float vc = s_v[c][pyi + 1][pxi + 4];
      const float vh = fmaf(a, lh[c], bb * mterm);
      n1 = fmaf(vc, vc, n1);
      const float u0 = s_v[c][pyi][pxi + 3];
      const float u1 = s_v[c][pyi][pxi + 4];
      const float u2 = s_v[c][pyi][pxi + 5];
      const float u3 = s_v[c][pyi + 1][pxi + 3];
      const float u4 = s_v[c][pyi + 1][pxi + 5];
      const float u5 = s_v[c][pyi + 2][pxi + 3];
      const float u6 = s_v[c][pyi + 2][pxi + 4];
      const float u7 = s_v[c][pyi + 2][pxi + 5];
      dot[0] = fmaf(vc, u0, dot[0]); n2[0] = fmaf(u0, u0, n2[0]);
      dot[1] = fmaf(vc, u1, dot[1]); n2[1] = fmaf(u1, u1, n2[1]);
      dot[2] = fmaf(vc, u2, dot[2]); n2[2] = fmaf(u2, u2, n2[2]);
      dot[3] = fmaf(vc, u3, dot[3]); n2[3] = fmaf(u3, u3, n2[3]);
      dot[4] = fmaf(vc, u4, dot[4]); n2[4] = fmaf(u4, u4, n2[4]);
      dot[5] = fmaf(vc, u5, dot[5]); n2[5] = fmaf(u5, u5, n2[5]);
      dot[6] = fmaf(vc, u6, dot[6]); n2[6] = fmaf(u6, u6, n2[6]);
      dot[7] = fmaf(vc, u7, dot[7]); n2[7] = fmaf(u7, u7, n2[7]);
      const float4 mw0 = *reinterpret_cast<const float4*>(&s_mw[cg][0]);
      const float4 mw1 = *reinterpret_cast<const float4*>(&s_mw[cg][4]);
      const float4 hw0 = *reinterpret_cast<const float4*>(&s_hw[cg][0]);
      const float4 hw1 = *reinterpret_cast<const float4*>(&s_hw[cg][4]);
      z[0] = fmaf(mw0.x, vc, fmaf(hw0.x, vh, z[0]));
      z[1] = fmaf(mw0.y, vc, fmaf(hw0.y, vh, z[1]));
      z[2] = fmaf(mw0.z, vc, fmaf(hw0.z, vh, z[2]));
      z[3] = fmaf(mw0.w, vc, fmaf(hw0.w, vh, z[3]));
      z[4] = fmaf(mw1.x, vc, fmaf(hw1.x, vh, z[4]));
      z[5] = fmaf(mw1.y, vc, fmaf(hw1.y, vh, z[5]));
      z[6] = fmaf(mw1.z, vc, fmaf(hw1.z, vh, z[6]));
      z[7] = fmaf(mw1.w, vc, fmaf(hw1.w, vh, z[7]));
    }
  }

  const float n1c = fmaxf(sqrtf(n1), 1e-8f);
  float df[8];
#pragma unroll
  for (int k = 0; k < 8; ++k)
    df[k] = dot[k] / (n1c * fmaxf(sqrtf(n2[k]), 1e-8f));

  float off[8];
#pragma unroll
  for (int o = 0; o < 8; ++o) {
    float t1 = s_bias[1][o];
#pragma unroll
    for (int j = 0; j < 8; ++j) t1 = fmaf(s_dir[o][j], df[j], t1);
    const float zz = z[o] + s_bias[0][o];
    off[o] = t1 / (1.f + expf(-zz));
  }

  // -------- bilinear sample this thread's pixel for all 64 channels --------
  float* outB = out + (size_t)(b * C_) * planeSz + hl * WL_ + wl;
#pragma unroll
  for (int g = 0; g < GRP; ++g) {
    const float ix = fminf(fmaxf(2.f * wl + 0.5f + off[g], 0.f), (float)(W_ - 1));
    const float iy = fminf(fmaxf(2.f * hl + 0.5f + off[GRP + g], 0.f), (float)(H_ - 1));
    const float x0f = floorf(ix), y0f = floorf(iy);
    const float wx = ix - x0f, wy = iy - y0f;
    const int x0 = (int)x0f, y0 = (int)y0f;
    const float w00 = (1.f - wx) * (1.f - wy), w01 = wx * (1.f - wy);
    const float w10 = (1.f - wx) * wy,        w11 = wx * wy;
    float* oc = outB + (size_t)(g * 16) * planeSz;
    if (USE_XB) {
      const unsigned short* pc = xb + (size_t)(b * C_ + g * 16) * (H_ * W_);
      if (__builtin_expect(((x0 | y0) & 1) == 0, 1)) {
#pragma unroll 4
        for (int c2 = 0; c2 < 16; ++c2) {
          const ushort2 r0 = *reinterpret_cast<const ushort2*>(pc + y0 * W_ + x0);
          const ushort2 r1 = *reinterpret_cast<const ushort2*>(pc + (y0 + 1) * W_ + x0);
          *oc = fmaf(bf2f(r0.x), w00, fmaf(bf2f(r0.y), w01,
                fmaf(bf2f(r1.x), w10, bf2f(r1.y) * w11)));
          pc += H_ * W_;
          oc += planeSz;
        }
      } else {
        const int x1 = min(x0 + 1, W_ - 1), y1 = min(y0 + 1, H_ - 1);
#pragma unroll 4
        for (int c2 = 0; c2 < 16; ++c2) {
          const float v00 = bf2f(pc[y0 * W_ + x0]);
          const float v01 = bf2f(pc[y0 * W_ + x1]);
          const float v10 = bf2f(pc[y1 * W_ + x0]);
          const float v11 = bf2f(pc[y1 * W_ + x1]);
          *oc = fmaf(v00, w00, fmaf(v01, w01, fmaf(v10, w10, v11 * w11)));
          pc += H_ * W_;
          oc += planeSz;
        }
      }
    } else {
      const float* pc = x + (size_t)(b * C_ + g * 16) * (H_ * W_);
      if (__builtin_expect(((x0 | y0) & 1) == 0, 1)) {
#pragma unroll 4
        for (int c2 = 0; c2 < 16; ++c2) {
          const float2 r0 = *reinterpret_cast<const float2*>(pc + y0 * W_ + x0);
          const float2 r1 = *reinterpret_cast<const float2*>(pc + (y0 + 1) * W_ + x0);
          *oc = fmaf(r0.x, w00, fmaf(r0.y, w01, fmaf(r1.x, w10, r1.y * w11)));
          pc += H_ * W_;
          oc += planeSz;
        }
      } else {
        const int x1 = min(x0 + 1, W_ - 1), y1 = min(y0 + 1, H_ - 1);
#pragma unroll 4
        for (int c2 = 0; c2 < 16; ++c2) {
          const float v00 = pc[y0 * W_ + x0];
          const float v01 = pc[y0 * W_ + x1];
          const float v10 = pc[y1 * W_ + x0];
          const float v11 = pc[y1 * W_ + x1];
          *oc = fmaf(v00, w00, fmaf(v01, w01, fmaf(v10, w10, v11 * w11)));
          pc += H_ * W_;
          oc += planeSz;
        }
      }
    }
  }
}

extern "C" void kernel_launch(void* const* d_in, const int* in_sizes, int n_in,
                              void* d_out, int out_size, void* d_ws, size_t ws_size,
                              hipStream_t stream) {
  const float* x = (const float*)d_in[0];
  const float* gn_gamma = (const float*)d_in[1];
  const float* gn_beta = (const float*)d_in[2];
  const float* hp_weight = (const float*)d_in[3];
  const float* dir_w = (const float*)d_in[4];
  const float* dir_b = (const float*)d_in[5];
  const float* mag_w = (const float*)d_in[6];
  const float* mag_b = (const float*)d_in[7];
  const float* hfg_w = (const float*)d_in[8];
  const float* hfg_b = (const float*)d_in[9];
  float* out = (float*)d_out;

  // ws layout
  float* ws = (float*)d_ws;
  float* partials = ws;                                   // 8192 floats (32 KB)
  __hip_bfloat16* px = (__hip_bfloat16*)(ws + 8192);      // 2,097,152 bf16 (4 MB)
  __hip_bfloat16* pL = px + (size_t)B_ * C_ * HL_ * WL_;  // 2,097,152 bf16 (4 MB)
  unsigned short* xb = (unsigned short*)(pL + (size_t)B_ * C_ * HL_ * WL_);  // 33.5M bf16 (67 MB)

  const size_t need = 32768 + 2u * 4194304u + 67108864u;
  const bool use_xb = (ws_size >= need);

  if (use_xb) {
    k2_fused<1><<<B_ * C_ * 8, 256, 0, stream>>>(x, hp_weight, px, pL, xb, partials);
    k34_fused<1><<<B_ * (HL_ / TS) * (WL_ / TS), 256, 0, stream>>>(
        x, xb, px, pL, partials, gn_gamma, gn_beta, dir_w, dir_b,
        mag_w, mag_b, hfg_w, hfg_b, out);
  } else {
    k2_fused<0><<<B_ * C_ * 8, 256, 0, stream>>>(x, hp_weight, px, pL, xb, partials);
    k34_fused<0><<<B_ * (HL_ / TS) * (WL_ / TS), 256, 0, stream>>>(
        x, xb, px, pL, partials, gn_gamma, gn_beta, dir_w, dir_b,
        mag_w, mag_b, hfg_w, hfg_b, out);
  }
}

// Round 16
// 89.616 us; speedup vs baseline: 1.0946x; 1.0946x over previous
//
#include <hip/hip_runtime.h>
#include <hip/hip_bf16.h>
#include <math.h>

// Problem constants
#define B_ 8
#define C_ 64
#define H_ 256
#define W_ 256
#define HL_ 128
#define WL_ 128
#define GN_G 8
#define CPG 8
#define GRP 4
#define OC_ 8
#define GROUP_ELEMS (CPG * H_ * W_)   // 524288

#define TILE_H 16       // low-res rows per k2 block
#define XROWS 34        // hi-res rows staged (2*16 + 2 halo)
#define EOW 132         // even/odd array row stride

__device__ __forceinline__ float bf2f(unsigned short u) {
  return __uint_as_float(((unsigned)u) << 16);
}

// ---------------- Kernel 2 (v3): fused GN-partials + pool(x) + pool(L(x)), bf16 out ----------------
__global__ __launch_bounds__(256) void k2_fused(const float* __restrict__ x,
                                                const float* __restrict__ hpw,
                                                __hip_bfloat16* __restrict__ px,
                                                __hip_bfloat16* __restrict__ pL,
                                                float* __restrict__ partials) {
  __shared__ float E[XROWS][EOW];
  __shared__ float O[XROWS][EOW];
  __shared__ float rs[4], rs2[4];
  const int t = threadIdx.x;
  const int blk = blockIdx.x;
  const int tileIdx = blk & 7;
  const int bc = blk >> 3;               // b*64+c
  const int c = bc & 63;
  const int hl0 = tileIdx * TILE_H;
  const float* plane = x + (size_t)bc * (H_ * W_);
  const int y0 = 2 * hl0 - 1;

  if (t < XROWS * 2) {
    const int r = t >> 1;
    if (t & 1) E[r][128] = 0.f; else O[r][0] = 0.f;
  }

  float s = 0.f, s2 = 0.f;
  for (int i = 0; i < 9; ++i) {
    const int q = t + i * 256;
    if (q >= XROWS * 64) break;
    const int r = q >> 6;
    const int k = q & 63;
    const int y = y0 + r;
    float4 v = make_float4(0.f, 0.f, 0.f, 0.f);
    if ((unsigned)y < (unsigned)H_)
      v = *reinterpret_cast<const float4*>(plane + y * W_ + (k << 2));
    E[r][2 * k]     = v.x;
    E[r][2 * k + 1] = v.z;
    O[r][2 * k + 1] = v.y;
    O[r][2 * k + 2] = v.w;
    if (r >= 1 && r <= 32) {
      s  += v.x + v.y + v.z + v.w;
      s2 += v.x * v.x + v.y * v.y + v.z * v.z + v.w * v.w;
    }
  }
#pragma unroll
  for (int off = 32; off > 0; off >>= 1) {
    s  += __shfl_down(s, off, 64);
    s2 += __shfl_down(s2, off, 64);
  }
  if ((t & 63) == 0) { rs[t >> 6] = s; rs2[t >> 6] = s2; }
  __syncthreads();
  if (t == 0) {
    partials[blk * 2 + 0] = rs[0] + rs[1] + rs[2] + rs[3];
    partials[blk * 2 + 1] = rs2[0] + rs2[1] + rs2[2] + rs2[3];
  }

  float w[9];
#pragma unroll
  for (int i = 0; i < 9; ++i) w[i] = hpw[c * 9 + i];

  const int wl = t & 127;
  const int hs = (t >> 7) * 8;
  const int rbase = 2 * hs;
  float win[4][4];
#pragma unroll
  for (int j = 0; j < 4; ++j) {
    win[j][0] = O[rbase + j][wl];
    win[j][1] = E[rbase + j][wl];
    win[j][2] = O[rbase + j][wl + 1];
    win[j][3] = E[rbase + j][wl + 1];
  }

  int outIdx = (bc * HL_ + (hl0 + hs)) * WL_ + wl;
#pragma unroll
  for (int i = 0; i < 8; ++i) {
    float pr[4][3];
#pragma unroll
    for (int j = 0; j < 4; ++j)
#pragma unroll
      for (int d = 0; d < 3; ++d) pr[j][d] = win[j][d] + win[j][d + 1];
    float hfsum = 0.f;
    float q11 = 0.f;
#pragma unroll
    for (int j = 0; j < 3; ++j)
#pragma unroll
      for (int d = 0; d < 3; ++d) {
        const float qq = pr[j][d] + pr[j + 1][d];
        hfsum = fmaf(w[j * 3 + d], qq, hfsum);
        if (j == 1 && d == 1) q11 = qq;
      }
    px[outIdx] = __float2bfloat16(0.25f * q11);
    pL[outIdx] = __float2bfloat16(0.25f * hfsum);
    outIdx += WL_;
    if (i < 7) {
      const int rn = rbase + 2 * i + 4;
#pragma unroll
      for (int d = 0; d < 4; ++d) {
        win[0][d] = win[2][d];
        win[1][d] = win[3][d];
      }
      win[2][0] = O[rn][wl];     win[2][1] = E[rn][wl];
      win[2][2] = O[rn][wl + 1]; win[2][3] = E[rn][wl + 1];
      win[3][0] = O[rn + 1][wl];     win[3][1] = E[rn + 1][wl];
      win[3][2] = O[rn + 1][wl + 1]; win[3][3] = E[rn + 1][wl + 1];
    }
  }
}

// ---------------- Kernel 34 (v5): inline GN-finalize + dbuf offsets + f32 sample ----------------
// R13's best-measured k34 (dbuf, f32 x-gather) + k1_finish folded into the prologue.
#define TS 16
__global__ __launch_bounds__(256) void k34_fused(const float* __restrict__ x,
                                                 const __hip_bfloat16* __restrict__ px,
                                                 const __hip_bfloat16* __restrict__ pL,
                                                 const float* __restrict__ partials,
                                                 const float* __restrict__ gamma,
                                                 const float* __restrict__ beta,
                                                 const float* __restrict__ dir_w,
                                                 const float* __restrict__ dir_b,
                                                 const float* __restrict__ mag_w,
                                                 const float* __restrict__ mag_b,
                                                 const float* __restrict__ hfg_w,
                                                 const float* __restrict__ hfg_b,
                                                 float* __restrict__ out) {
  __shared__ float s_v[2][16][18][24];  // 55.3 KB dbuf: affine xl tile + halo (f32)
  __shared__ float s_mw[C_][OC_];
  __shared__ float s_hw[C_][OC_];
  __shared__ float s_dir[OC_][8];
  __shared__ float s_ab2[C_][2];
  __shared__ float s_bias[2][OC_];

  const int tid = threadIdx.x;
  const int bx = blockIdx.x;
  const int tx = bx & 7, ty = (bx >> 3) & 7, b = bx >> 6;
  const int hl0 = ty * TS, wl0 = tx * TS;
  const size_t planeSz = (size_t)HL_ * WL_;

  for (int i = tid; i < OC_ * C_; i += 256) {
    const int o = i >> 6, c = i & 63;
    s_mw[c][o] = mag_w[i];
    s_hw[c][o] = hfg_w[i];
  }
  if (tid < 64) s_dir[tid >> 3][tid & 7] = dir_w[tid];
  if (tid < OC_) { s_bias[0][tid] = mag_b[tid] + hfg_b[tid]; s_bias[1][tid] = dir_b[tid]; }
  // inline GN finalize: per-channel affine from partials (L2-resident)
  if (tid < 64) {
    const int c = tid, g = c >> 3;
    float S = 0.f, S2 = 0.f;
    for (int c2 = g * CPG; c2 < g * CPG + CPG; ++c2)
#pragma unroll
      for (int p2 = 0; p2 < 8; ++p2) {
        const int blk2 = (b * 64 + c2) * 8 + p2;
        S  += partials[blk2 * 2 + 0];
        S2 += partials[blk2 * 2 + 1];
      }
    const float N = (float)GROUP_ELEMS;
    const float mean = S / N;
    const float var = fmaxf(S2 / N - mean * mean, 0.f);
    const float a = rsqrtf(var + 1e-5f) * gamma[c];
    s_ab2[c][0] = a;
    s_ab2[c][1] = beta[c] - mean * a;
  }
  __syncthreads();   // s_ab2 ready (stage reads it)

  auto stage = [&](int cc, int sel) {
    for (int q = tid; q < 16 * 18 * 6; q += 256) {
      const int c = q / 108, rem = q % 108, r = rem / 6, f4 = rem % 6;
      const int cg = cc * 16 + c;
      const int gy = hl0 - 1 + r;
      const int gx0 = wl0 - 4 + f4 * 4;
      const float a = s_ab2[cg][0], bb = s_ab2[cg][1];
      const __hip_bfloat16* pp = px + (size_t)(b * C_ + cg) * planeSz + gy * WL_ + gx0;
      float4 v = make_float4(0.f, 0.f, 0.f, 0.f);
      if ((unsigned)gy < (unsigned)HL_) {
        if (gx0 >= 0 && gx0 + 3 < WL_) {
          const ushort4 rv = *reinterpret_cast<const ushort4*>(pp);   // 8B-aligned
          v.x = fmaf(a, bf2f(rv.x), bb); v.y = fmaf(a, bf2f(rv.y), bb);
          v.z = fmaf(a, bf2f(rv.z), bb); v.w = fmaf(a, bf2f(rv.w), bb);
        } else {
          const unsigned short* ps = reinterpret_cast<const unsigned short*>(pp);
          if ((unsigned)(gx0 + 0) < (unsigned)WL_) v.x = fmaf(a, bf2f(ps[0]), bb);
          if ((unsigned)(gx0 + 1) < (unsigned)WL_) v.y = fmaf(a, bf2f(ps[1]), bb);
          if ((unsigned)(gx0 + 2) < (unsigned)WL_) v.z = fmaf(a, bf2f(ps[2]), bb);
          if ((unsigned)(gx0 + 3) < (unsigned)WL_) v.w = fmaf(a, bf2f(ps[3]), bb);
        }
      }
      *reinterpret_cast<float4*>(&s_v[sel][c][r][f4 * 4]) = v;
    }
  };

  const int pxi = tid & 15, pyi = tid >> 4;
  const int hl = hl0 + pyi, wl = wl0 + pxi;
  const float mterm = 0.5f * ((hl == 0) + (hl == HL_ - 1) + (wl == 0) + (wl == WL_ - 1));

  float dot[8], n2[8], z[8], n1 = 0.f;
#pragma unroll
  for (int k = 0; k < 8; ++k) { dot[k] = 0.f; n2[k] = 0.f; z[k] = 0.f; }

  stage(0, 0);
  __syncthreads();

  for (int cc = 0; cc < 4; ++cc) {
    if (cc < 3) stage(cc + 1, (cc + 1) & 1);
    const int sel = cc & 1;
    float lh[16];
    {
      const unsigned short* lp = reinterpret_cast<const unsigned short*>(
          pL + (size_t)(b * C_ + cc * 16) * planeSz + hl * WL_ + wl);
#pragma unroll
      for (int c = 0; c < 16; ++c) lh[c] = bf2f(lp[c * planeSz]);
    }
#pragma unroll
    for (int c = 0; c < 16; ++c) {
      const int cg = cc * 16 + c;
      const float a = s_ab2[cg][0], bb = s_ab2[cg][1];
      const float vc = s_v[sel][c][pyi + 1][pxi + 4];
      const float vh = fmaf(a, lh[c], bb * mterm);
      n1 = fmaf(vc, vc, n1);
      const float u0 = s_v[sel][c][pyi][pxi + 3];
      const float u1 = s_v[sel][c][pyi][pxi + 4];
      const float u2 = s_v[sel][c][pyi][pxi + 5];
      const float u3 = s_v[sel][c][pyi + 1][pxi + 3];
      const float u4 = s_v[sel][c][pyi + 1][pxi + 5];
      const float u5 = s_v[sel][c][pyi + 2][pxi + 3];
      const float u6 = s_v[sel][c][pyi + 2][pxi + 4];
      const float u7 = s_v[sel][c][pyi + 2][pxi + 5];
      dot[0] = fmaf(vc, u0, dot[0]); n2[0] = fmaf(u0, u0, n2[0]);
      dot[1] = fmaf(vc, u1, dot[1]); n2[1] = fmaf(u1, u1, n2[1]);
      dot[2] = fmaf(vc, u2, dot[2]); n2[2] = fmaf(u2, u2, n2[2]);
      dot[3] = fmaf(vc, u3, dot[3]); n2[3] = fmaf(u3, u3, n2[3]);
      dot[4] = fmaf(vc, u4, dot[4]); n2[4] = fmaf(u4, u4, n2[4]);
      dot[5] = fmaf(vc, u5, dot[5]); n2[5] = fmaf(u5, u5, n2[5]);
      dot[6] = fmaf(vc, u6, dot[6]); n2[6] = fmaf(u6, u6, n2[6]);
      dot[7] = fmaf(vc, u7, dot[7]); n2[7] = fmaf(u7, u7, n2[7]);
      const float4 mw0 = *reinterpret_cast<const float4*>(&s_mw[cg][0]);
      const float4 mw1 = *reinterpret_cast<const float4*>(&s_mw[cg][4]);
      const float4 hw0 = *reinterpret_cast<const float4*>(&s_hw[cg][0]);
      const float4 hw1 = *reinterpret_cast<const float4*>(&s_hw[cg][4]);
      z[0] = fmaf(mw0.x, vc, fmaf(hw0.x, vh, z[0]));
      z[1] = fmaf(mw0.y, vc, fmaf(hw0.y, vh, z[1]));
      z[2] = fmaf(mw0.z, vc, fmaf(hw0.z, vh, z[2]));
      z[3] = fmaf(mw0.w, vc, fmaf(hw0.w, vh, z[3]));
      z[4] = fmaf(mw1.x, vc, fmaf(hw1.x, vh, z[4]));
      z[5] = fmaf(mw1.y, vc, fmaf(hw1.y, vh, z[5]));
      z[6] = fmaf(mw1.z, vc, fmaf(hw1.z, vh, z[6]));
      z[7] = fmaf(mw1.w, vc, fmaf(hw1.w, vh, z[7]));
    }
    __syncthreads();
  }

  const float n1c = fmaxf(sqrtf(n1), 1e-8f);
  float df[8];
#pragma unroll
  for (int k = 0; k < 8; ++k)
    df[k] = dot[k] / (n1c * fmaxf(sqrtf(n2[k]), 1e-8f));

  float off[8];
#pragma unroll
  for (int o = 0; o < 8; ++o) {
    float t1 = s_bias[1][o];
#pragma unroll
    for (int j = 0; j < 8; ++j) t1 = fmaf(s_dir[o][j], df[j], t1);
    const float zz = z[o] + s_bias[0][o];
    off[o] = t1 / (1.f + expf(-zz));
  }

  // -------- bilinear sample this thread's pixel for all 64 channels (f32 x, L3-hit) --------
  const float* planeB = x + (size_t)(b * C_) * (H_ * W_);
  float* outB = out + (size_t)(b * C_) * planeSz + hl * WL_ + wl;
#pragma unroll
  for (int g = 0; g < GRP; ++g) {
    const float ix = fminf(fmaxf(2.f * wl + 0.5f + off[g], 0.f), (float)(W_ - 1));
    const float iy = fminf(fmaxf(2.f * hl + 0.5f + off[GRP + g], 0.f), (float)(H_ - 1));
    const float x0f = floorf(ix), y0f = floorf(iy);
    const float wx = ix - x0f, wy = iy - y0f;
    const int x0 = (int)x0f, y0 = (int)y0f;
    const float w00 = (1.f - wx) * (1.f - wy), w01 = wx * (1.f - wy);
    const float w10 = (1.f - wx) * wy,        w11 = wx * wy;
    const float* pc = planeB + (size_t)(g * 16) * (H_ * W_);
    float* oc = outB + (size_t)(g * 16) * planeSz;
    if (__builtin_expect(((x0 | y0) & 1) == 0, 1)) {
#pragma unroll 4
      for (int c2 = 0; c2 < 16; ++c2) {
        const float2 r0 = *reinterpret_cast<const float2*>(pc + y0 * W_ + x0);
        const float2 r1 = *reinterpret_cast<const float2*>(pc + (y0 + 1) * W_ + x0);
        *oc = fmaf(r0.x, w00, fmaf(r0.y, w01, fmaf(r1.x, w10, r1.y * w11)));
        pc += H_ * W_;
        oc += planeSz;
      }
    } else {
      const int x1 = min(x0 + 1, W_ - 1), y1 = min(y0 + 1, H_ - 1);
#pragma unroll 4
      for (int c2 = 0; c2 < 16; ++c2) {
        const float v00 = pc[y0 * W_ + x0];
        const float v01 = pc[y0 * W_ + x1];
        const float v10 = pc[y1 * W_ + x0];
        const float v11 = pc[y1 * W_ + x1];
        *oc = fmaf(v00, w00, fmaf(v01, w01, fmaf(v10, w10, v11 * w11)));
        pc += H_ * W_;
        oc += planeSz;
      }
    }
  }
}

extern "C" void kernel_launch(void* const* d_in, const int* in_sizes, int n_in,
                              void* d_out, int out_size, void* d_ws, size_t ws_size,
                              hipStream_t stream) {
  const float* x = (const float*)d_in[0];
  const float* gn_gamma = (const float*)d_in[1];
  const float* gn_beta = (const float*)d_in[2];
  const float* hp_weight = (const float*)d_in[3];
  const float* dir_w = (const float*)d_in[4];
  const float* dir_b = (const float*)d_in[5];
  const float* mag_w = (const float*)d_in[6];
  const float* mag_b = (const float*)d_in[7];
  const float* hfg_w = (const float*)d_in[8];
  const float* hfg_b = (const float*)d_in[9];
  float* out = (float*)d_out;

  // ws layout
  float* ws = (float*)d_ws;
  float* partials = ws;                                   // 8192 floats (32 KB)
  __hip_bfloat16* px = (__hip_bfloat16*)(ws + 8192);      // 2,097,152 bf16 (4 MB)
  __hip_bfloat16* pL = px + (size_t)B_ * C_ * HL_ * WL_;  // 2,097,152 bf16 (4 MB)

  k2_fused<<<B_ * C_ * 8, 256, 0, stream>>>(x, hp_weight, px, pL, partials);
  k34_fused<<<B_ * (HL_ / TS) * (WL_ / TS), 256, 0, stream>>>(
      x, px, pL, partials, gn_gamma, gn_beta, dir_w, dir_b,
      mag_w, mag_b, hfg_w, hfg_b, out);
}